// Round 24
// baseline (59.859 us; speedup 1.0000x reference)
//
#include <hip/hip_runtime.h>
#include <math.h>

constexpr int NB = 8, NC = 64, NO = 64, NH = 64, NW = 64;

using f32x4 = __attribute__((ext_vector_type(4))) float;
using s16x8 = __attribute__((ext_vector_type(8))) short;
using u32x4 = __attribute__((ext_vector_type(4))) unsigned int;

// packed f32x2 -> bf16x2 (RNE), v_cvt_pk_bf16_f32 (no builtin on gfx950)
__device__ __forceinline__ unsigned int pk2(float lo, float hi) {
    unsigned int r;
    asm("v_cvt_pk_bf16_f32 %0, %1, %2" : "=v"(r) : "v"(lo), "v"(hi));
    return r;
}
__device__ __forceinline__ unsigned short f2bf(float f) {
    unsigned u = __builtin_bit_cast(unsigned, f);
    return (unsigned short)((u + 0x7fffu + ((u >> 16) & 1u)) >> 16);
}
__device__ __forceinline__ float bf2f(unsigned short s) {
    unsigned u = ((unsigned)s) << 16;
    return __builtin_bit_cast(float, u);
}

// ATOM-SPLIT design: R19's loop is latency-bound at 2 waves/SIMD (loop model 5.5us LDS /
// 2.7 VALU / 1.2 MFMA vs ~15us measured). out = SUM_k patch_k * SUM_a att*relu distributes:
// wave pairs split the 4 atoms (2 each) over the SAME (h,w,o) tile and merge ONCE post-loop
// -> 4 waves/SIMD with UNCHANGED per-CU W/bias LDS traffic (R20's failure avoided).
// Block 1024 thr = 16 waves = hrow(4) x ahalf(2) x whalf(2), 2 n-tiles each.
// Block tile 4h x 64w x 16o; grid 512 = b(8) x hq(16) x osub(4) -> 2 rounds/CU, round-2
// prologues overlap round-1 tails. XCD swizzle (R19, -17%): osub-siblings share bx%8.
// MFMA A = W (rows=o), B = x (cols=w). D: row(o)=q*4+reg, col(w)=c0 -> coalesced stores.
// LDS 122 KB (Xs 32K -> merge buf; Ws 72K; Patch 15.5K; bias 2.3K), 1 blk/CU resident.
// 64-VGPR budget (1024 thr): live ~60 (xf16+out8+tsum8+attv4+inflight) -> fits (R13/R20).
__global__ __launch_bounds__(1024, 1)
void acda_kernel(const float* __restrict__ x, const float* __restrict__ w_gen,
                 const float* __restrict__ b_gen, const float* __restrict__ pos_enc,
                 float* __restrict__ out)
{
    __shared__ unsigned short Xs[256 * 64];       // 32 KB [loc = hs*64+w][c] swz; merge buf after loop
    __shared__ unsigned short Ws[16 * 36 * 64];   // 72 KB [o_l][t][c] bf16, XOR-swizzled
    __shared__ unsigned short Patch[6 * 66 * 20]; // 15.5 KB [hhi][wwi][o_l(16)+pad4] bf16
    __shared__ float BiasL[36 * 16];              // 2.3 KB [t][o_l]

    const int tid  = threadIdx.x;
    const int lane = tid & 63;
    const int wv   = tid >> 6;            // 0..15
    const int c0   = lane & 15, q = lane >> 4;
    const int hrow  = wv >> 2;            // 0..3
    const int ahalf = (wv >> 1) & 1;      // atom pair
    const int whalf = wv & 1;             // w half

    // ---- XCD-aware remap (T1, R19-verified): osub-siblings share bx%8 ----
    const int bx0  = blockIdx.x;          // 0..511
    const int xcd  = bx0 & 7;
    const int idx  = bx0 >> 3;            // 0..63
    const int osub = idx & 3;
    const int g    = xcd + 8 * (idx >> 2);    // 0..127 = (b, hq) group
    const int b    = g >> 4;
    const int hq   = g & 15;
    const int hbase = hq * 4;
    const int obase = osub * 16;
    const size_t xB = (size_t)b * NC * NH * NW;

    // ---- stage Ws: w_gen[(obase+o_l)*36 + t][c] f32 -> Ws[o_l][t][c] bf16 swz (4608 x 16B) ----
    for (int u = tid; u < 4608; u += 1024) {
        const int o_l = u / 288;
        const int r   = u - o_l * 288;
        const int t   = r >> 3, cseg = r & 7;
        const float* src = w_gen + ((size_t)(obase + o_l) * 36 + t) * NC + cseg * 8;
        const float4 v0 = *reinterpret_cast<const float4*>(src);
        const float4 v1 = *reinterpret_cast<const float4*>(src + 4);
        u32x4 pk;
        pk[0] = pk2(v0.x, v0.y); pk[1] = pk2(v0.z, v0.w);
        pk[2] = pk2(v1.x, v1.y); pk[3] = pk2(v1.z, v1.w);
        const int byte = (o_l * 36 + t) * 128 + ((cseg * 16) ^ ((o_l & 7) << 4));
        *reinterpret_cast<u32x4*>(reinterpret_cast<char*>(Ws) + byte) = pk;
    }
    // ---- stage Xs: x[b,c,hbase+hs,w] -> Xs[loc = hs*64+w][c] bf16 swz (rows always valid) ----
    {
        const int w = lane;
#pragma unroll
        for (int i = 0; i < 2; ++i) {
            const int pair = wv * 2 + i;          // 32 (hs, oct) pairs
            const int hs = pair >> 3, oct = pair & 7;
            const float* src = x + xB + (size_t)(oct * 8) * (NH * NW) + (hbase + hs) * NW + w;
            u32x4 pkv;
#pragma unroll
            for (int j = 0; j < 4; ++j)
                pkv[j] = pk2(src[(size_t)(2 * j) * (NH * NW)], src[(size_t)(2 * j + 1) * (NH * NW)]);
            const int loc  = hs * 64 + w;
            const int byte = loc * 128 + ((oct * 16) ^ ((loc & 7) << 4));
            *reinterpret_cast<u32x4*>(reinterpret_cast<char*>(Xs) + byte) = pkv;
        }
    }
    // ---- stage Patch: x[b,obase+o_l,hbase-1+hhi,w] -> Patch[hhi][w+1][o_l] bf16 ----
    {
        const int o_l = tid >> 6, w = tid & 63;
        const float* xo = x + xB + (size_t)(obase + o_l) * (NH * NW);
#pragma unroll
        for (int hhi = 0; hhi < 6; ++hhi) {
            const int hh = hbase - 1 + hhi;
            const float v = (hh >= 0 && hh < NH) ? xo[hh * NW + w] : 0.0f;
            Patch[(hhi * 66 + w + 1) * 20 + o_l] = f2bf(v);
        }
    }
    if (tid < 192) {   // zero halo columns wwi = 0, 65 (6 rows x 2 sides x 16 o)
        const int hhi = tid >> 5, side = (tid >> 4) & 1, o_l = tid & 15;
        Patch[(hhi * 66 + (side ? 65 : 0)) * 20 + o_l] = 0;
    }
    // ---- stage bias ----
    if (tid < 576) {
        const int t = tid >> 4, o_l = tid & 15;
        BiasL[tid] = b_gen[(obase + o_l) * 36 + t];
    }
    __syncthreads();   // everything staged

    // ---- x fragments: 2 n-tiles ----
    s16x8 xf[2][2];
#pragma unroll
    for (int nt = 0; nt < 2; ++nt) {
        const int loc = hrow * 64 + whalf * 32 + nt * 16 + c0;
#pragma unroll
        for (int kh2 = 0; kh2 < 2; ++kh2) {
            const int byte = loc * 128 + ((kh2 * 64 + q * 16) ^ ((loc & 7) << 4));
            xf[nt][kh2] = *reinterpret_cast<s16x8*>(reinterpret_cast<char*>(Xs) + byte);
        }
    }
    __syncthreads();   // all xf reads done (Xs region becomes merge buffer after the loop)

    // ---- attention attv[a2][nt] for this wave's 2 atoms ----
    const float gy = -1.0f + (2.0f / 63.0f) * (float)(hbase + hrow);
    float attv[2][2];
#pragma unroll
    for (int a2 = 0; a2 < 2; ++a2) {
        const int a = ahalf * 2 + a2;
        const float px = pos_enc[2 * a], py = pos_enc[2 * a + 1];
#pragma unroll
        for (int nt = 0; nt < 2; ++nt) {
            const float gx = -1.0f + (2.0f / 63.0f) * (float)(whalf * 32 + nt * 16 + c0);
            const float dx = gx - px, dy = gy - py;
            attv[a2][nt] = __expf(-(dx * dx + dy * dy));
        }
    }

    const int wswz = (c0 & 7) << 4;
    const char* wrowp = reinterpret_cast<const char*>(Ws) + c0 * (36 * 128);

    float outacc[2][4] = {};

#pragma unroll
    for (int k = 0; k < 9; ++k) {
        float tsum[2][4] = {};
#pragma unroll
        for (int a2 = 0; a2 < 2; ++a2) {
            const int t = (ahalf * 2 + a2) * 9 + k;
            const s16x8 wf0 = *reinterpret_cast<const s16x8*>(wrowp + t * 128 + ((q * 16) ^ wswz));
            const s16x8 wf1 = *reinterpret_cast<const s16x8*>(wrowp + t * 128 + ((64 + q * 16) ^ wswz));
            const f32x4 bb  = *reinterpret_cast<const f32x4*>(BiasL + t * 16 + q * 4);
#pragma unroll
            for (int nt = 0; nt < 2; ++nt) {
                f32x4 acc = bb;
                acc = __builtin_amdgcn_mfma_f32_16x16x32_bf16(wf0, xf[nt][0], acc, 0, 0, 0);
                acc = __builtin_amdgcn_mfma_f32_16x16x32_bf16(wf1, xf[nt][1], acc, 0, 0, 0);
                const float at = attv[a2][nt];
#pragma unroll
                for (int r = 0; r < 4; ++r)
                    tsum[nt][r] = fmaf(at, fmaxf(acc[r], 0.f), tsum[nt][r]);
            }
        }
        const int kh = k / 3, kw = k - 3 * kh;
#pragma unroll
        for (int nt = 0; nt < 2; ++nt) {
            const ushort4 pu = *reinterpret_cast<const ushort4*>(
                reinterpret_cast<const char*>(Patch) +
                (((hrow + kh) * 66 + whalf * 32 + nt * 16 + c0 + kw) * 20 + q * 4) * 2);
            outacc[nt][0] = fmaf(tsum[nt][0], bf2f(pu.x), outacc[nt][0]);
            outacc[nt][1] = fmaf(tsum[nt][1], bf2f(pu.y), outacc[nt][1]);
            outacc[nt][2] = fmaf(tsum[nt][2], bf2f(pu.z), outacc[nt][2]);
            outacc[nt][3] = fmaf(tsum[nt][3], bf2f(pu.w), outacc[nt][3]);
        }
    }

    // ---- atom-pair merge: ahalf=1 writes partials to the dead Xs region; ahalf=0 adds ----
    float* MB = reinterpret_cast<float*>(Xs);
    const int slot = ((tid >> 8) << 7) | (tid & 127);   // tid with ahalf bit (bit 7) removed
    if (ahalf == 1) {
        float* d = MB + slot * 8;
#pragma unroll
        for (int nt = 0; nt < 2; ++nt)
#pragma unroll
            for (int r = 0; r < 4; ++r) d[nt * 4 + r] = outacc[nt][r];
    }
    __syncthreads();
    if (ahalf == 0) {
        const float* s = MB + slot * 8;
        const int h = hbase + hrow;
#pragma unroll
        for (int nt = 0; nt < 2; ++nt) {
            const int wcol = whalf * 32 + nt * 16 + c0;
#pragma unroll
            for (int r = 0; r < 4; ++r) {
                const int o = obase + q * 4 + r;
                out[(((size_t)b * NO + o) * NH + h) * NW + wcol] = outacc[nt][r] + s[nt * 4 + r];
            }
        }
    }
}

extern "C" void kernel_launch(void* const* d_in, const int* in_sizes, int n_in,
                              void* d_out, int out_size, void* d_ws, size_t ws_size,
                              hipStream_t stream) {
    const float* x       = (const float*)d_in[0];
    const float* w_gen   = (const float*)d_in[1];
    const float* b_gen   = (const float*)d_in[2];
    const float* pos_enc = (const float*)d_in[3];
    float* out = (float*)d_out;

    dim3 grid(NB * 16 * 4);   // 512 workgroups -> 2 rounds of 1 block/CU
    dim3 block(1024);
    hipLaunchKernelGGL(acda_kernel, grid, block, 0, stream,
                       x, w_gen, b_gen, pos_enc, out);
}

// Round 25
// 59.221 us; speedup vs baseline: 1.0108x; 1.0108x over previous
//
#include <hip/hip_runtime.h>
#include <math.h>

constexpr int NB = 8, NC = 64, NO = 64, NH = 64, NW = 64;

using f32x4 = __attribute__((ext_vector_type(4))) float;
using s16x8 = __attribute__((ext_vector_type(8))) short;
using u32x4 = __attribute__((ext_vector_type(4))) unsigned int;

// packed f32x2 -> bf16x2 (RNE), v_cvt_pk_bf16_f32 (no builtin on gfx950)
__device__ __forceinline__ unsigned int pk2(float lo, float hi) {
    unsigned int r;
    asm("v_cvt_pk_bf16_f32 %0, %1, %2" : "=v"(r) : "v"(lo), "v"(hi));
    return r;
}
__device__ __forceinline__ unsigned short f2bf(float f) {
    unsigned u = __builtin_bit_cast(unsigned, f);
    return (unsigned short)((u + 0x7fffu + ((u >> 16) & 1u)) >> 16);
}
__device__ __forceinline__ float bf2f(unsigned short s) {
    unsigned u = ((unsigned)s) << 16;
    return __builtin_bit_cast(float, u);
}

// [R24 atom-split, byte-identical] + SINGLE DELTA: amdgpu_waves_per_eu(4,4).
// R24 failed ONLY by register allocation: VGPR=64 (live set ~70-80 -> 256B/thread spill,
// WRITE 137MB). launch_bounds(1024,1) = 16 waves/CU = 4 waves/SIMD permits 128 VGPRs
// (m69 occupancy steps); waves_per_eu(4,4) is CONSISTENT with that (unlike R8, where
// launch_bounds(512,4) itself demanded 8 waves/EU) and should lift the budget to 128.
// Design under test: out = SUM_k patch_k * SUM_a att*relu distributes -> wave pairs split
// the 4 atoms (2 each) over the same (h,w,o) tile, merge once post-loop via LDS ->
// 4 waves/SIMD latency hiding at UNCHANGED per-CU W/bias LDS traffic (R20's cost avoided).
// Block 1024 thr = 16 waves = hrow(4) x ahalf(2) x whalf(2), 2 n-tiles each.
// Block tile 4h x 64w x 16o; grid 512 -> 2 rounds/CU. XCD swizzle (R19-verified, -17%).
// MFMA A = W (rows=o), B = x (cols=w). D: row(o)=q*4+reg, col(w)=c0 -> coalesced stores.
// LDS 122 KB (Xs 32K -> merge buf; Ws 72K; Patch 15.5K; bias 2.3K).
__global__ __launch_bounds__(1024, 1) __attribute__((amdgpu_waves_per_eu(4, 4)))
void acda_kernel(const float* __restrict__ x, const float* __restrict__ w_gen,
                 const float* __restrict__ b_gen, const float* __restrict__ pos_enc,
                 float* __restrict__ out)
{
    __shared__ unsigned short Xs[256 * 64];       // 32 KB [loc = hs*64+w][c] swz; merge buf after loop
    __shared__ unsigned short Ws[16 * 36 * 64];   // 72 KB [o_l][t][c] bf16, XOR-swizzled
    __shared__ unsigned short Patch[6 * 66 * 20]; // 15.5 KB [hhi][wwi][o_l(16)+pad4] bf16
    __shared__ float BiasL[36 * 16];              // 2.3 KB [t][o_l]

    const int tid  = threadIdx.x;
    const int lane = tid & 63;
    const int wv   = tid >> 6;            // 0..15
    const int c0   = lane & 15, q = lane >> 4;
    const int hrow  = wv >> 2;            // 0..3
    const int ahalf = (wv >> 1) & 1;      // atom pair
    const int whalf = wv & 1;             // w half

    // ---- XCD-aware remap (T1, R19-verified): osub-siblings share bx%8 ----
    const int bx0  = blockIdx.x;          // 0..511
    const int xcd  = bx0 & 7;
    const int idx  = bx0 >> 3;            // 0..63
    const int osub = idx & 3;
    const int g    = xcd + 8 * (idx >> 2);    // 0..127 = (b, hq) group
    const int b    = g >> 4;
    const int hq   = g & 15;
    const int hbase = hq * 4;
    const int obase = osub * 16;
    const size_t xB = (size_t)b * NC * NH * NW;

    // ---- stage Ws: w_gen[(obase+o_l)*36 + t][c] f32 -> Ws[o_l][t][c] bf16 swz (4608 x 16B) ----
    for (int u = tid; u < 4608; u += 1024) {
        const int o_l = u / 288;
        const int r   = u - o_l * 288;
        const int t   = r >> 3, cseg = r & 7;
        const float* src = w_gen + ((size_t)(obase + o_l) * 36 + t) * NC + cseg * 8;
        const float4 v0 = *reinterpret_cast<const float4*>(src);
        const float4 v1 = *reinterpret_cast<const float4*>(src + 4);
        u32x4 pk;
        pk[0] = pk2(v0.x, v0.y); pk[1] = pk2(v0.z, v0.w);
        pk[2] = pk2(v1.x, v1.y); pk[3] = pk2(v1.z, v1.w);
        const int byte = (o_l * 36 + t) * 128 + ((cseg * 16) ^ ((o_l & 7) << 4));
        *reinterpret_cast<u32x4*>(reinterpret_cast<char*>(Ws) + byte) = pk;
    }
    // ---- stage Xs: x[b,c,hbase+hs,w] -> Xs[loc = hs*64+w][c] bf16 swz (rows always valid) ----
    {
        const int w = lane;
#pragma unroll
        for (int i = 0; i < 2; ++i) {
            const int pair = wv * 2 + i;          // 32 (hs, oct) pairs
            const int hs = pair >> 3, oct = pair & 7;
            const float* src = x + xB + (size_t)(oct * 8) * (NH * NW) + (hbase + hs) * NW + w;
            u32x4 pkv;
#pragma unroll
            for (int j = 0; j < 4; ++j)
                pkv[j] = pk2(src[(size_t)(2 * j) * (NH * NW)], src[(size_t)(2 * j + 1) * (NH * NW)]);
            const int loc  = hs * 64 + w;
            const int byte = loc * 128 + ((oct * 16) ^ ((loc & 7) << 4));
            *reinterpret_cast<u32x4*>(reinterpret_cast<char*>(Xs) + byte) = pkv;
        }
    }
    // ---- stage Patch: x[b,obase+o_l,hbase-1+hhi,w] -> Patch[hhi][w+1][o_l] bf16 ----
    {
        const int o_l = tid >> 6, w = tid & 63;
        const float* xo = x + xB + (size_t)(obase + o_l) * (NH * NW);
#pragma unroll
        for (int hhi = 0; hhi < 6; ++hhi) {
            const int hh = hbase - 1 + hhi;
            const float v = (hh >= 0 && hh < NH) ? xo[hh * NW + w] : 0.0f;
            Patch[(hhi * 66 + w + 1) * 20 + o_l] = f2bf(v);
        }
    }
    if (tid < 192) {   // zero halo columns wwi = 0, 65 (6 rows x 2 sides x 16 o)
        const int hhi = tid >> 5, side = (tid >> 4) & 1, o_l = tid & 15;
        Patch[(hhi * 66 + (side ? 65 : 0)) * 20 + o_l] = 0;
    }
    // ---- stage bias ----
    if (tid < 576) {
        const int t = tid >> 4, o_l = tid & 15;
        BiasL[tid] = b_gen[(obase + o_l) * 36 + t];
    }
    __syncthreads();   // everything staged

    // ---- x fragments: 2 n-tiles ----
    s16x8 xf[2][2];
#pragma unroll
    for (int nt = 0; nt < 2; ++nt) {
        const int loc = hrow * 64 + whalf * 32 + nt * 16 + c0;
#pragma unroll
        for (int kh2 = 0; kh2 < 2; ++kh2) {
            const int byte = loc * 128 + ((kh2 * 64 + q * 16) ^ ((loc & 7) << 4));
            xf[nt][kh2] = *reinterpret_cast<s16x8*>(reinterpret_cast<char*>(Xs) + byte);
        }
    }
    __syncthreads();   // all xf reads done (Xs region becomes merge buffer after the loop)

    // ---- attention attv[a2][nt] for this wave's 2 atoms ----
    const float gy = -1.0f + (2.0f / 63.0f) * (float)(hbase + hrow);
    float attv[2][2];
#pragma unroll
    for (int a2 = 0; a2 < 2; ++a2) {
        const int a = ahalf * 2 + a2;
        const float px = pos_enc[2 * a], py = pos_enc[2 * a + 1];
#pragma unroll
        for (int nt = 0; nt < 2; ++nt) {
            const float gx = -1.0f + (2.0f / 63.0f) * (float)(whalf * 32 + nt * 16 + c0);
            const float dx = gx - px, dy = gy - py;
            attv[a2][nt] = __expf(-(dx * dx + dy * dy));
        }
    }

    const int wswz = (c0 & 7) << 4;
    const char* wrowp = reinterpret_cast<const char*>(Ws) + c0 * (36 * 128);

    float outacc[2][4] = {};

#pragma unroll
    for (int k = 0; k < 9; ++k) {
        float tsum[2][4] = {};
#pragma unroll
        for (int a2 = 0; a2 < 2; ++a2) {
            const int t = (ahalf * 2 + a2) * 9 + k;
            const s16x8 wf0 = *reinterpret_cast<const s16x8*>(wrowp + t * 128 + ((q * 16) ^ wswz));
            const s16x8 wf1 = *reinterpret_cast<const s16x8*>(wrowp + t * 128 + ((64 + q * 16) ^ wswz));
            const f32x4 bb  = *reinterpret_cast<const f32x4*>(BiasL + t * 16 + q * 4);
#pragma unroll
            for (int nt = 0; nt < 2; ++nt) {
                f32x4 acc = bb;
                acc = __builtin_amdgcn_mfma_f32_16x16x32_bf16(wf0, xf[nt][0], acc, 0, 0, 0);
                acc = __builtin_amdgcn_mfma_f32_16x16x32_bf16(wf1, xf[nt][1], acc, 0, 0, 0);
                const float at = attv[a2][nt];
#pragma unroll
                for (int r = 0; r < 4; ++r)
                    tsum[nt][r] = fmaf(at, fmaxf(acc[r], 0.f), tsum[nt][r]);
            }
        }
        const int kh = k / 3, kw = k - 3 * kh;
#pragma unroll
        for (int nt = 0; nt < 2; ++nt) {
            const ushort4 pu = *reinterpret_cast<const ushort4*>(
                reinterpret_cast<const char*>(Patch) +
                (((hrow + kh) * 66 + whalf * 32 + nt * 16 + c0 + kw) * 20 + q * 4) * 2);
            outacc[nt][0] = fmaf(tsum[nt][0], bf2f(pu.x), outacc[nt][0]);
            outacc[nt][1] = fmaf(tsum[nt][1], bf2f(pu.y), outacc[nt][1]);
            outacc[nt][2] = fmaf(tsum[nt][2], bf2f(pu.z), outacc[nt][2]);
            outacc[nt][3] = fmaf(tsum[nt][3], bf2f(pu.w), outacc[nt][3]);
        }
    }

    // ---- atom-pair merge: ahalf=1 writes partials to the dead Xs region; ahalf=0 adds ----
    float* MB = reinterpret_cast<float*>(Xs);
    const int slot = ((tid >> 8) << 7) | (tid & 127);   // tid with ahalf bit (bit 7) removed
    if (ahalf == 1) {
        float* d = MB + slot * 8;
#pragma unroll
        for (int nt = 0; nt < 2; ++nt)
#pragma unroll
            for (int r = 0; r < 4; ++r) d[nt * 4 + r] = outacc[nt][r];
    }
    __syncthreads();
    if (ahalf == 0) {
        const float* s = MB + slot * 8;
        const int h = hbase + hrow;
#pragma unroll
        for (int nt = 0; nt < 2; ++nt) {
            const int wcol = whalf * 32 + nt * 16 + c0;
#pragma unroll
            for (int r = 0; r < 4; ++r) {
                const int o = obase + q * 4 + r;
                out[(((size_t)b * NO + o) * NH + h) * NW + wcol] = outacc[nt][r] + s[nt * 4 + r];
            }
        }
    }
}

extern "C" void kernel_launch(void* const* d_in, const int* in_sizes, int n_in,
                              void* d_out, int out_size, void* d_ws, size_t ws_size,
                              hipStream_t stream) {
    const float* x       = (const float*)d_in[0];
    const float* w_gen   = (const float*)d_in[1];
    const float* b_gen   = (const float*)d_in[2];
    const float* pos_enc = (const float*)d_in[3];
    float* out = (float*)d_out;

    dim3 grid(NB * 16 * 4);   // 512 workgroups -> 2 rounds of 1 block/CU
    dim3 block(1024);
    hipLaunchKernelGGL(acda_kernel, grid, block, 0, stream,
                       x, w_gen, b_gen, pos_enc, out);
}

// Round 26
// 21.578 us; speedup vs baseline: 2.7741x; 2.7446x over previous
//
#include <hip/hip_runtime.h>
#include <math.h>

constexpr int NB = 8, NC = 64, NO = 64, NH = 64, NW = 64;

using f32x4 = __attribute__((ext_vector_type(4))) float;
using s16x8 = __attribute__((ext_vector_type(8))) short;
using u32x4 = __attribute__((ext_vector_type(4))) unsigned int;

// packed f32x2 -> bf16x2 (RNE), v_cvt_pk_bf16_f32 (no builtin on gfx950)
__device__ __forceinline__ unsigned int pk2(float lo, float hi) {
    unsigned int r;
    asm("v_cvt_pk_bf16_f32 %0, %1, %2" : "=v"(r) : "v"(lo), "v"(hi));
    return r;
}
__device__ __forceinline__ unsigned short f2bf(float f) {
    unsigned u = __builtin_bit_cast(unsigned, f);
    return (unsigned short)((u + 0x7fffu + ((u >> 16) & 1u)) >> 16);
}
__device__ __forceinline__ float bf2f(unsigned short s) {
    unsigned u = ((unsigned)s) << 16;
    return __builtin_bit_cast(float, u);
}

// FINAL KERNEL — R19-verified optimum (21.6 us, reproduced 3x; 24x over round-1 baseline).
// Structure: grid 256 = 1 block/CU; block 512 thr = 8 waves; block tile 8h x 64w x 16o;
// wave wv = hrow owns a full h-row (4 n-tiles of 16 w) -> maximal per-wave W-LDS
// amortization (72 frag reads / 1024 outputs — every occupancy-raising variant measured
// 2x W-traffic and regressed: R20/R24; every W-streaming variant paid 9 barrier drains:
// R15/R16).
// XCD-aware blockIdx swizzle (T1, the single biggest win, -17%): the 4 osub-siblings of
// each (b,hoct) group read the SAME 164 KB x-slab; remapping them to share bx%8 puts them
// on one XCD's L2 so the slab is fetched once (xcd = bx&7, idx = bx>>3, bijective).
// k-OUTER / a-INNER with tsum: patch read once per k (4x fewer than per-tap).
// MFMA A = W (rows=o), B = x (cols=w). D: row(o)=q*4+reg, col(w)=c0 -> coalesced stores.
// LDS 138.3 KB (arena: Xs 64KB -> xf regs -> Patch 26.4KB; Ws 72KB; bias 2.3KB), 1 blk/CU.
// launch_bounds(512,1) -> 128-VGPR budget; live ~110 -> no spill. (Spill ledger: (512,4)
// and all 1024-thr blocks pin 64 VGPRs -> 100+ MB scratch traffic, 2.5-9x slowdowns.)
__global__ __launch_bounds__(512, 1)
void acda_kernel(const float* __restrict__ x, const float* __restrict__ w_gen,
                 const float* __restrict__ b_gen, const float* __restrict__ pos_enc,
                 float* __restrict__ out)
{
    __shared__ __align__(16) unsigned char arena[65536];  // Xs [512 loc][64c] bf16 swz -> Patch [10][66][20] bf16
    __shared__ unsigned short Ws[16 * 36 * 64];           // 72 KB [o_l][t][c] bf16, XOR-swizzled
    __shared__ float BiasL[36 * 16];                      // 2.3 KB [t][o_l]

    const int tid  = threadIdx.x;
    const int lane = tid & 63;
    const int wv   = tid >> 6;           // 0..7 = hrow
    const int c0   = lane & 15, q = lane >> 4;
    const int hrow = wv;

    // ---- XCD-aware remap (T1): siblings (same b,hoct; osub=0..3) share bx%8 ----
    const int bx0  = blockIdx.x;         // 0..255
    const int xcd  = bx0 & 7;
    const int idx  = bx0 >> 3;           // 0..31 within XCD
    const int osub = idx & 3;
    const int g    = xcd + 8 * (idx >> 2);   // 0..63 = (b,hoct) group
    const int b    = g >> 3;
    const int hoct = g & 7;
    const int hbase = hoct * 8;
    const int obase = osub * 16;
    const size_t xB = (size_t)b * NC * NH * NW;

    // ---- stage Ws: w_gen[(obase+o_l)*36 + t][c] f32 -> Ws[o_l][t][c] bf16 swz (4608 x 16B) ----
    for (int u = tid; u < 4608; u += 512) {
        const int o_l = u / 288;
        const int r   = u - o_l * 288;
        const int t   = r >> 3, cseg = r & 7;
        const float* src = w_gen + ((size_t)(obase + o_l) * 36 + t) * NC + cseg * 8;
        const float4 v0 = *reinterpret_cast<const float4*>(src);
        const float4 v1 = *reinterpret_cast<const float4*>(src + 4);
        u32x4 pk;
        pk[0] = pk2(v0.x, v0.y); pk[1] = pk2(v0.z, v0.w);
        pk[2] = pk2(v1.x, v1.y); pk[3] = pk2(v1.z, v1.w);
        const int byte = (o_l * 36 + t) * 128 + ((cseg * 16) ^ ((o_l & 7) << 4));
        *reinterpret_cast<u32x4*>(reinterpret_cast<char*>(Ws) + byte) = pk;
    }
    // ---- stage Xs into arena: x[b,c,hbase+hs,w] -> [loc = hs*64+w][c] bf16 swz ----
    {
        const int w = lane;
#pragma unroll
        for (int i = 0; i < 8; ++i) {
            const int pair = wv * 8 + i;          // 64 (hs, oct) pairs
            const int hs = pair >> 3, oct = pair & 7;
            const float* src = x + xB + (size_t)(oct * 8) * (NH * NW) + (hbase + hs) * NW + w;
            u32x4 pkv;
#pragma unroll
            for (int j = 0; j < 4; ++j)
                pkv[j] = pk2(src[(size_t)(2 * j) * (NH * NW)], src[(size_t)(2 * j + 1) * (NH * NW)]);
            const int loc  = hs * 64 + w;
            const int byte = loc * 128 + ((oct * 16) ^ ((loc & 7) << 4));
            *reinterpret_cast<u32x4*>(arena + byte) = pkv;
        }
    }
    // ---- stage bias: BiasL[t*16 + o_l] = b_gen[(obase+o_l)*36 + t] ----
    for (int i = tid; i < 576; i += 512) {
        const int t = i >> 4, o_l = i & 15;
        BiasL[i] = b_gen[(obase + o_l) * 36 + t];
    }
    __syncthreads();   // Xs ready

    // ---- x fragments: 4 n-tiles (full h-row per wave) ----
    s16x8 xf[4][2];
#pragma unroll
    for (int nt = 0; nt < 4; ++nt) {
        const int loc = hrow * 64 + nt * 16 + c0;
#pragma unroll
        for (int kh2 = 0; kh2 < 2; ++kh2) {
            const int byte = loc * 128 + ((kh2 * 64 + q * 16) ^ ((loc & 7) << 4));
            xf[nt][kh2] = *reinterpret_cast<s16x8*>(arena + byte);
        }
    }
    __syncthreads();   // all Xs reads done; arena becomes Patch

    // ---- stage Patch: x[b,obase+o_l,hbase-1+hhi,w] -> Patch[hhi][w+1][o_l] bf16 ----
    unsigned short* Patch = reinterpret_cast<unsigned short*>(arena);
    {
        const int o_l = tid >> 5, w2 = (tid & 31) * 2;
        const float* xo = x + xB + (size_t)(obase + o_l) * (NH * NW);
#pragma unroll
        for (int hhi = 0; hhi < 10; ++hhi) {
            const int hh = hbase - 1 + hhi;
            float2 v = {0.f, 0.f};
            if (hh >= 0 && hh < NH) v = *reinterpret_cast<const float2*>(xo + hh * NW + w2);
            Patch[(hhi * 66 + w2 + 1) * 20 + o_l] = f2bf(v.x);
            Patch[(hhi * 66 + w2 + 2) * 20 + o_l] = f2bf(v.y);
        }
    }
    if (tid < 320) {   // zero halo columns wwi = 0, 65
        const int hhi = tid >> 5, side = (tid >> 4) & 1, o_l = tid & 15;
        Patch[(hhi * 66 + (side ? 65 : 0)) * 20 + o_l] = 0;
    }
    __syncthreads();   // Ws, Patch, BiasL ready

    // ---- attention attv[a][nt] ----
    const float gy = -1.0f + (2.0f / 63.0f) * (float)(hbase + hrow);
    float attv[4][4];
#pragma unroll
    for (int a = 0; a < 4; ++a) {
        const float px = pos_enc[2 * a], py = pos_enc[2 * a + 1];
#pragma unroll
        for (int nt = 0; nt < 4; ++nt) {
            const float gx = -1.0f + (2.0f / 63.0f) * (float)(nt * 16 + c0);
            const float dx = gx - px, dy = gy - py;
            attv[a][nt] = __expf(-(dx * dx + dy * dy));
        }
    }

    const int wswz = (c0 & 7) << 4;
    const char* wrowp = reinterpret_cast<const char*>(Ws) + c0 * (36 * 128);

    float outacc[4][4] = {};

#pragma unroll
    for (int k = 0; k < 9; ++k) {
        float tsum[4][4] = {};
#pragma unroll
        for (int a = 0; a < 4; ++a) {
            const int t = a * 9 + k;
            const s16x8 wf0 = *reinterpret_cast<const s16x8*>(wrowp + t * 128 + ((q * 16) ^ wswz));
            const s16x8 wf1 = *reinterpret_cast<const s16x8*>(wrowp + t * 128 + ((64 + q * 16) ^ wswz));
            const f32x4 bb  = *reinterpret_cast<const f32x4*>(BiasL + t * 16 + q * 4);
#pragma unroll
            for (int nt = 0; nt < 4; ++nt) {
                f32x4 acc = bb;
                acc = __builtin_amdgcn_mfma_f32_16x16x32_bf16(wf0, xf[nt][0], acc, 0, 0, 0);
                acc = __builtin_amdgcn_mfma_f32_16x16x32_bf16(wf1, xf[nt][1], acc, 0, 0, 0);
                const float at = attv[a][nt];
#pragma unroll
                for (int r = 0; r < 4; ++r)
                    tsum[nt][r] = fmaf(at, fmaxf(acc[r], 0.f), tsum[nt][r]);
            }
        }
        const int kh = k / 3, kw = k - 3 * kh;
#pragma unroll
        for (int nt = 0; nt < 4; ++nt) {
            const ushort4 pu = *reinterpret_cast<const ushort4*>(
                reinterpret_cast<const char*>(Patch) +
                (((hrow + kh) * 66 + nt * 16 + c0 + kw) * 20 + q * 4) * 2);
            outacc[nt][0] = fmaf(tsum[nt][0], bf2f(pu.x), outacc[nt][0]);
            outacc[nt][1] = fmaf(tsum[nt][1], bf2f(pu.y), outacc[nt][1]);
            outacc[nt][2] = fmaf(tsum[nt][2], bf2f(pu.z), outacc[nt][2]);
            outacc[nt][3] = fmaf(tsum[nt][3], bf2f(pu.w), outacc[nt][3]);
        }
    }

    // ---- coalesced stores: 16 consecutive w per 16-lane group ----
    const int h = hbase + hrow;
#pragma unroll
    for (int nt = 0; nt < 4; ++nt) {
        const int wcol = nt * 16 + c0;
#pragma unroll
        for (int r = 0; r < 4; ++r) {
            const int o = obase + q * 4 + r;
            out[(((size_t)b * NO + o) * NH + h) * NW + wcol] = outacc[nt][r];
        }
    }
}

extern "C" void kernel_launch(void* const* d_in, const int* in_sizes, int n_in,
                              void* d_out, int out_size, void* d_ws, size_t ws_size,
                              hipStream_t stream) {
    const float* x       = (const float*)d_in[0];
    const float* w_gen   = (const float*)d_in[1];
    const float* b_gen   = (const float*)d_in[2];
    const float* pos_enc = (const float*)d_in[3];
    float* out = (float*)d_out;

    dim3 grid(NB * 8 * 4);   // 256 workgroups = 1 per CU
    dim3 block(512);
    hipLaunchKernelGGL(acda_kernel, grid, block, 0, stream,
                       x, w_gen, b_gen, pos_enc, out);
}